// Round 7
// baseline (1213.831 us; speedup 1.0000x reference)
//
#include <hip/hip_runtime.h>
#include <cmath>

#define LSEQ 2048
#define NBATCH 8

typedef __attribute__((ext_vector_type(8))) short short8;
typedef __attribute__((ext_vector_type(4))) float f32x4;
union U16x8 { short8 v; unsigned short u[8]; };

__device__ __forceinline__ float silu_f(float x) { return x / (1.0f + __expf(-x)); }
__device__ __forceinline__ float softplus_f(float x) {
    return fmaxf(x, 0.0f) + log1pf(__expf(-fabsf(x)));
}
__device__ __forceinline__ unsigned short f2bf(float f) {   // RNE fp32->bf16
    unsigned int u = __float_as_uint(f);
    u += 0x7FFFu + ((u >> 16) & 1u);
    return (unsigned short)(u >> 16);
}
__device__ __forceinline__ float bf2f(unsigned short h) {
    return __uint_as_float(((unsigned int)h) << 16);
}
__device__ __forceinline__ void gload_lds16(const void* g, void* l) {
    __builtin_amdgcn_global_load_lds((const __attribute__((address_space(1))) void*)g,
                                     (__attribute__((address_space(3))) void*)l, 16, 0, 0);
}

// ---------------------------------------------------------------------------
// Wave-level vectorized epilogue: stage the wave's 64x64 f32 tile through a
// private LDS strip (16 rows at a time), then coalesced 16B/lane stores.
// OMODE: 0=f32, 1=bf16, 2=f32+softplus, 3=bf16+softplus (bias pre-activation).
// ---------------------------------------------------------------------------
template<int OMODE>
__device__ __forceinline__ void wave_epilogue(
    float* es, const f32x4 (&acc)[4][4], const float* bias,
    void* Cout, int ldc, int row0, int col0, int lane)
{
    const int l15 = lane & 15, l4 = lane >> 4;
#pragma unroll
    for (int mi = 0; mi < 4; ++mi) {
#pragma unroll
        for (int ni = 0; ni < 4; ++ni) {
            const int lc = ni * 16 + l15;
            const float bv = bias ? bias[col0 + lc] : 0.0f;
#pragma unroll
            for (int r = 0; r < 4; ++r) {
                float v = acc[mi][ni][r] + bv;
                if (OMODE >= 2) v = softplus_f(v);
                es[(l4 * 4 + r) * 64 + lc] = v;
            }
        }
        __asm__ volatile("s_waitcnt lgkmcnt(0)" ::: "memory");
#pragma unroll
        for (int ps = 0; ps < 2; ++ps) {
            const int rr = (lane >> 3) + ps * 8;
            const int cg = (lane & 7) * 8;
            const float4 v0 = *(const float4*)&es[rr * 64 + cg];
            const float4 v1 = *(const float4*)&es[rr * 64 + cg + 4];
            const size_t base = (size_t)(row0 + mi * 16 + rr) * ldc + col0 + cg;
            if (OMODE & 1) {
                U16x8 o;
                o.u[0] = f2bf(v0.x); o.u[1] = f2bf(v0.y); o.u[2] = f2bf(v0.z); o.u[3] = f2bf(v0.w);
                o.u[4] = f2bf(v1.x); o.u[5] = f2bf(v1.y); o.u[6] = f2bf(v1.z); o.u[7] = f2bf(v1.w);
                *(short8*)&((unsigned short*)Cout)[base] = o.v;
            } else {
                *(float4*)&((float*)Cout)[base] = v0;
                *(float4*)&((float*)Cout)[base + 4] = v1;
            }
        }
        __asm__ volatile("s_waitcnt lgkmcnt(0)" ::: "memory");
    }
}

// fwd/bwd operand pairs; blockIdx.z selects direction
struct GemmPair {
    const unsigned short* A[2];
    const unsigned short* A2[2];   // DUAL second A (second K-half, row-reversed)
    const unsigned short* W[2];
    const float* bias[2];
    void* C[2];
};

// ---------------------------------------------------------------------------
// bf16 MFMA GEMM (NT): C[m,n] = A[m,:].W[n,:] (+bias). 256 thr = 4 waves,
// each wave 64x64 via 4x4 mfma_f32_16x16x32_bf16. BK=32.
// blockIdx.x = m-tile (gridDim.x % 8 == 0 keeps same-A blocks on one XCD).
// DUAL: k>=1024 reads A2 at row^2047, lda (final merge, K=2048).
// ---------------------------------------------------------------------------
template<int WGM, int WGN, int OMODE, int DUAL>
__global__ __launch_bounds__(WGM* WGN * 64) void gemm_mfma(GemmPair gp, int lda, int ldw,
                                                           int ldc, int K)
{
    constexpr int NW = WGM * WGN;
    constexpr int TM = WGM * 64, TN = WGN * 64;
    __shared__ unsigned short As[TM * 32];
    __shared__ unsigned short Bs[TN * 32];
    __shared__ float Es[NW * 1024];
    const int dir = blockIdx.z;
    const unsigned short* A  = gp.A[dir];
    const unsigned short* A2 = gp.A2[dir];
    const unsigned short* W  = gp.W[dir];
    const float* bias        = gp.bias[dir];
    void* Cout               = gp.C[dir];

    const int tid = threadIdx.x;
    const int wave = tid >> 6, lane = tid & 63;
    const int wm = wave / WGN, wn = wave % WGN;
    const int m0 = blockIdx.x * TM, n0 = blockIdx.y * TN;
    const int l15 = lane & 15, l4 = lane >> 4;
    const int srow = lane >> 2, schunk = (lane & 3) * 8;

    f32x4 acc[4][4] = {};

    for (int k0 = 0; k0 < K; k0 += 32) {
        __syncthreads();
        for (int s = wave; s < TM / 16; s += NW) {
            const int gr = m0 + s * 16 + srow;
            const unsigned short* g;
            if (DUAL && k0 >= 1024)
                g = A2 + (size_t)(gr ^ (LSEQ - 1)) * lda + (k0 - 1024) + schunk;
            else
                g = A + (size_t)gr * lda + k0 + schunk;
            gload_lds16(g, (char*)As + (size_t)s * 1024);
        }
        for (int s = wave; s < TN / 16; s += NW) {
            const int gr = n0 + s * 16 + srow;
            const unsigned short* g = W + (size_t)gr * ldw + k0 + schunk;
            gload_lds16(g, (char*)Bs + (size_t)s * 1024);
        }
        __syncthreads();
        short8 af[4], bfr[4];
#pragma unroll
        for (int mi = 0; mi < 4; ++mi)
            af[mi] = *(const short8*)&As[(wm * 64 + mi * 16 + l15) * 32 + l4 * 8];
#pragma unroll
        for (int ni = 0; ni < 4; ++ni)
            bfr[ni] = *(const short8*)&Bs[(wn * 64 + ni * 16 + l15) * 32 + l4 * 8];
#pragma unroll
        for (int mi = 0; mi < 4; ++mi)
#pragma unroll
            for (int ni = 0; ni < 4; ++ni)
                acc[mi][ni] = __builtin_amdgcn_mfma_f32_16x16x32_bf16(af[mi], bfr[ni], acc[mi][ni], 0, 0, 0);
    }

    wave_epilogue<OMODE>(Es + wave * 1024, acc, bias, Cout, ldc,
                         m0 + wm * 64, n0 + wn * 64, lane);
}

// ---------------------------------------------------------------------------
// Fused x-proj + dt-proj. Per block: 128 rows.
// Phase 1: dbl = xi @ xpw^T (128 x 64, K=1024); cols 0..31 -> LDS bf16 (dblh),
//          cols 32..63 (B,C) -> global f32 (ld 64).
// Phase 2: dt = softplus(dblh @ dtw^T + dtb) -> bf16 (128 x 1024).
// ---------------------------------------------------------------------------
struct XprojPair {
    const unsigned short* xi[2];
    const unsigned short* xpw[2];
    const unsigned short* dtw[2];
    const float* dtb[2];
    float* dbl[2];
    unsigned short* dt[2];
};

__global__ __launch_bounds__(256) void xproj_dt_k(XprojPair xp)
{
    __shared__ unsigned short As[128 * 32];   // phase1 A staging; phase2 holds dblh
    __shared__ unsigned short Bs[128 * 32];   // phase1 xpw (64 rows); phase2 dtw tile
    __shared__ float Es[4 * 1024];

    const int dir = blockIdx.z;
    const unsigned short* xi  = xp.xi[dir];
    const unsigned short* xpw = xp.xpw[dir];
    const unsigned short* dtw = xp.dtw[dir];
    const float* dtb          = xp.dtb[dir];
    float* dbl                = xp.dbl[dir];
    unsigned short* dt        = xp.dt[dir];

    const int tid = threadIdx.x;
    const int wave = tid >> 6, lane = tid & 63;
    const int wm = wave >> 1, wn = wave & 1;
    const int m0 = blockIdx.x * 128;
    const int l15 = lane & 15, l4 = lane >> 4;
    const int srow = lane >> 2, schunk = (lane & 3) * 8;

    // ---- phase 1: dbl (128 x 64), wave tile 64 x 32 ----
    f32x4 acc[4][2] = {};
    for (int k0 = 0; k0 < 1024; k0 += 32) {
        __syncthreads();
        for (int s = wave; s < 8; s += 4) {
            const int gr = m0 + s * 16 + srow;
            gload_lds16(xi + (size_t)gr * 1024 + k0 + schunk, (char*)As + (size_t)s * 1024);
        }
        {
            const int s = wave;
            const int gr = s * 16 + srow;
            gload_lds16(xpw + (size_t)gr * 1024 + k0 + schunk, (char*)Bs + (size_t)s * 1024);
        }
        __syncthreads();
        short8 af[4], bfr[2];
#pragma unroll
        for (int mi = 0; mi < 4; ++mi)
            af[mi] = *(const short8*)&As[(wm * 64 + mi * 16 + l15) * 32 + l4 * 8];
#pragma unroll
        for (int ni = 0; ni < 2; ++ni)
            bfr[ni] = *(const short8*)&Bs[(wn * 32 + ni * 16 + l15) * 32 + l4 * 8];
#pragma unroll
        for (int mi = 0; mi < 4; ++mi)
#pragma unroll
            for (int ni = 0; ni < 2; ++ni)
                acc[mi][ni] = __builtin_amdgcn_mfma_f32_16x16x32_bf16(af[mi], bfr[ni], acc[mi][ni], 0, 0, 0);
    }

    __syncthreads();   // everyone done reading As before reuse as dblh
#pragma unroll
    for (int mi = 0; mi < 4; ++mi)
#pragma unroll
        for (int ni = 0; ni < 2; ++ni)
#pragma unroll
            for (int r = 0; r < 4; ++r) {
                const int rl = wm * 64 + mi * 16 + l4 * 4 + r;     // 0..127
                const int col = wn * 32 + ni * 16 + l15;           // 0..63
                const float v = acc[mi][ni][r];
                if (col < 32) As[rl * 32 + col] = f2bf(v);          // dblh
                else          dbl[(size_t)(m0 + rl) * 64 + col] = v; // B,C
            }
    __syncthreads();

    // ---- phase 2: dt (128 x 1024), K=32; n-loop 8 x 128-wide tiles ----
    for (int n0 = 0; n0 < 1024; n0 += 128) {
        __syncthreads();
        for (int s = wave; s < 8; s += 4) {
            const int gr = n0 + s * 16 + srow;
            gload_lds16(dtw + (size_t)gr * 32 + schunk, (char*)Bs + (size_t)s * 1024);
        }
        __syncthreads();
        short8 af2[4], bf2r[4];
#pragma unroll
        for (int mi = 0; mi < 4; ++mi)
            af2[mi] = *(const short8*)&As[(wm * 64 + mi * 16 + l15) * 32 + l4 * 8];
#pragma unroll
        for (int ni = 0; ni < 4; ++ni)
            bf2r[ni] = *(const short8*)&Bs[(wn * 64 + ni * 16 + l15) * 32 + l4 * 8];
        f32x4 a2[4][4] = {};
#pragma unroll
        for (int mi = 0; mi < 4; ++mi)
#pragma unroll
            for (int ni = 0; ni < 4; ++ni)
                a2[mi][ni] = __builtin_amdgcn_mfma_f32_16x16x32_bf16(af2[mi], bf2r[ni], a2[mi][ni], 0, 0, 0);
        wave_epilogue<3>(Es + wave * 1024, a2, dtb, dt, 1024,
                         m0 + wm * 64, n0 + wn * 64, lane);
    }
}

// ---------------------------------------------------------------------------
// Combined weight for fused out-proj+final:
// Wcomb[n, d + dir*1024] = sum_j lin_w[n, j + dir*512] * ow_dir[j, d]  (bf16)
// ---------------------------------------------------------------------------
__global__ __launch_bounds__(256) void combine_k(
    const float* __restrict__ lin_w, const float* __restrict__ owf,
    const float* __restrict__ owb, unsigned short* __restrict__ Wcomb)
{
    const int dir = blockIdx.z;
    const float* ow = dir ? owb : owf;
    const int lane = threadIdx.x & 63;
    const int wave = threadIdx.x >> 6;
    const int n = blockIdx.y * 4 + wave;          // 0..511
    const int d = blockIdx.x * 256 + lane * 4;    // 0..1023
    float4 acc = {0.f, 0.f, 0.f, 0.f};
    const float* lrow = lin_w + (size_t)n * 1024 + dir * 512;
    for (int j = 0; j < 512; ++j) {
        const float s = lrow[j];
        const float4 v = *(const float4*)&ow[(size_t)j * 1024 + d];
        acc.x = fmaf(s, v.x, acc.x); acc.y = fmaf(s, v.y, acc.y);
        acc.z = fmaf(s, v.z, acc.z); acc.w = fmaf(s, v.w, acc.w);
    }
    ushort4 o;
    o.x = f2bf(acc.x); o.y = f2bf(acc.y); o.z = f2bf(acc.z); o.w = f2bf(acc.w);
    *(ushort4*)&Wcomb[(size_t)n * 2048 + dir * 1024 + d] = o;
}

// ---------------------------------------------------------------------------
// fp32 -> bf16 conversion: 6 weight segments, one launch.
// ---------------------------------------------------------------------------
struct CvtArgs { const float* s[6]; unsigned short* d[6]; int n[6]; };
__global__ __launch_bounds__(256) void cvt_k(CvtArgs a)
{
    const int sid = blockIdx.y;
    const float* s = a.s[sid];
    unsigned short* d = a.d[sid];
    const int n4 = a.n[sid] >> 2;
    for (int i = blockIdx.x * 256 + threadIdx.x; i < n4; i += gridDim.x * 256) {
        const float4 v = ((const float4*)s)[i];
        ushort4 o; o.x = f2bf(v.x); o.y = f2bf(v.y); o.z = f2bf(v.z); o.w = f2bf(v.w);
        ((ushort4*)d)[i] = o;
    }
}
__global__ __launch_bounds__(256) void cvtx_k(const float* __restrict__ s,
                                              unsigned short* __restrict__ d, int n4)
{
    for (int i = blockIdx.x * 256 + threadIdx.x; i < n4; i += gridDim.x * 256) {
        const float4 v = ((const float4*)s)[i];
        ushort4 o; o.x = f2bf(v.x); o.y = f2bf(v.y); o.z = f2bf(v.z); o.w = f2bf(v.w);
        ((ushort4*)d)[i] = o;
    }
}

// ---------------------------------------------------------------------------
// Causal depthwise conv(4) + bias + SiLU, both dirs; bf16 in (xz cols 0..1023,
// ld 2048), bf16 out. Backward dir indexes reversed rows.
// ---------------------------------------------------------------------------
__global__ __launch_bounds__(256) void conv_silu_k(
    const unsigned short* __restrict__ xz_f, const float* __restrict__ cw_f,
    const float* __restrict__ cb_f, unsigned short* __restrict__ xi_f,
    const unsigned short* __restrict__ xz_b, const float* __restrict__ cw_b,
    const float* __restrict__ cb_b, unsigned short* __restrict__ xi_b)
{
    const int dir = blockIdx.y;
    const unsigned short* xz = dir ? xz_b : xz_f;
    const float* cw = dir ? cw_b : cw_f;
    const float* cb = dir ? cb_b : cb_f;
    unsigned short* xi = dir ? xi_b : xi_f;

    const int bt = blockIdx.x;
    const int b = bt >> 11;
    const int t = bt & (LSEQ - 1);
    const int d = threadIdx.x << 2;

    float w[4][4];
#pragma unroll
    for (int i = 0; i < 4; ++i) {
        const float4 wr = *(const float4*)&cw[(d + i) * 4];
        w[i][0] = wr.x; w[i][1] = wr.y; w[i][2] = wr.z; w[i][3] = wr.w;
    }
    float4 acc = *(const float4*)&cb[d];
#pragma unroll
    for (int k = 0; k < 4; ++k) {
        const int row = dir ? (LSEQ - 1 - t) + 3 - k : t - 3 + k;
        if ((unsigned)row < (unsigned)LSEQ) {
            const ushort4 v = *(const ushort4*)&xz[(size_t)(b * LSEQ + row) * 2048 + d];
            acc.x += w[0][k] * bf2f(v.x); acc.y += w[1][k] * bf2f(v.y);
            acc.z += w[2][k] * bf2f(v.z); acc.w += w[3][k] * bf2f(v.w);
        }
    }
    ushort4 st;
    st.x = f2bf(silu_f(acc.x)); st.y = f2bf(silu_f(acc.y));
    st.z = f2bf(silu_f(acc.z)); st.w = f2bf(silu_f(acc.w));
    *(ushort4*)&xi[(size_t)(b * LSEQ + t) * 1024 + d] = st;
}

// ---------------------------------------------------------------------------
// Selective scan (unchanged from round 6: 16ch x 16state, LDS [ch][t],
// DPP 16-lane reduce, register prefetch). Writes gated y bf16 over xi.
// ---------------------------------------------------------------------------
__device__ __forceinline__ float row_sum16(float x) {
    x += __int_as_float(__builtin_amdgcn_update_dpp(0, __float_as_int(x), 0xB1, 0xF, 0xF, false));  // quad xor1
    x += __int_as_float(__builtin_amdgcn_update_dpp(0, __float_as_int(x), 0x4E, 0xF, 0xF, false));  // quad xor2
    x += __int_as_float(__builtin_amdgcn_update_dpp(0, __float_as_int(x), 0x141, 0xF, 0xF, false)); // row_half_mirror
    x += __int_as_float(__builtin_amdgcn_update_dpp(0, __float_as_int(x), 0x140, 0xF, 0xF, false)); // row_mirror
    return x;
}

__global__ __launch_bounds__(256) void scan_k(
    const unsigned short* __restrict__ dt_f, unsigned short* __restrict__ xiy_f,
    const float* __restrict__ dbl_f, const unsigned short* __restrict__ xz_f,
    const float* __restrict__ Al_f, const float* __restrict__ Dp_f,
    const unsigned short* __restrict__ dt_b, unsigned short* __restrict__ xiy_b,
    const float* __restrict__ dbl_b, const unsigned short* __restrict__ xz_b,
    const float* __restrict__ Al_b, const float* __restrict__ Dp_b)
{
    __shared__ float sdt[16][68], sxi[16][68], sB[16][68], sC[16][68], sy[16][68];

    const int dir = blockIdx.z;
    const unsigned short* dt = dir ? dt_b : dt_f;
    unsigned short* xiy = dir ? xiy_b : xiy_f;
    const float* dbl = dir ? dbl_b : dbl_f;
    const unsigned short* zz = dir ? xz_b : xz_f;
    const float* Al = dir ? Al_b : Al_f;
    const float* Dpp = dir ? Dp_b : Dp_f;

    const int b = blockIdx.y, d0 = blockIdx.x << 4;
    const int tid = threadIdx.x;
    const int di = tid >> 4, n = tid & 15;
    const float Av = -expf(Al[(d0 + di) * 16 + n]);
    const int lr = tid >> 2, lc4 = (tid & 3) << 2;
    float dpv[4];
#pragma unroll
    for (int i = 0; i < 4; ++i) dpv[i] = Dpp[d0 + lc4 + i];

    ushort4 pdt, pxi, pz;
    float4 pB, pC;
    auto issue_loads = [&](int c) {
        const size_t r = (size_t)b * LSEQ + c * 64 + lr;
        pdt = *(const ushort4*)&dt[r * 1024 + d0 + lc4];
        pxi = *(const ushort4*)&xiy[r * 1024 + d0 + lc4];
        pB  = *(const float4*)&dbl[r * 64 + 32 + lc4];
        pC  = *(const float4*)&dbl[r * 64 + 48 + lc4];
    };
    issue_loads(0);

    float h = 0.0f;
    for (int c = 0; c < LSEQ / 64; ++c) {
        const int t0 = c * 64;
        __syncthreads();
        sdt[lc4 + 0][lr] = bf2f(pdt.x); sdt[lc4 + 1][lr] = bf2f(pdt.y);
        sdt[lc4 + 2][lr] = bf2f(pdt.z); sdt[lc4 + 3][lr] = bf2f(pdt.w);
        sxi[lc4 + 0][lr] = bf2f(pxi.x); sxi[lc4 + 1][lr] = bf2f(pxi.y);
        sxi[lc4 + 2][lr] = bf2f(pxi.z); sxi[lc4 + 3][lr] = bf2f(pxi.w);
        sB[lc4 + 0][lr] = pB.x; sB[lc4 + 1][lr] = pB.y; sB[lc4 + 2][lr] = pB.z; sB[lc4 + 3][lr] = pB.w;
        sC[lc4 + 0][lr] = pC.x; sC[lc4 + 1][lr] = pC.y; sC[lc4 + 2][lr] = pC.z; sC[lc4 + 3][lr] = pC.w;
        __syncthreads();

        if (c + 1 < LSEQ / 64) issue_loads(c + 1);
        {
            const int tz = dir ? (LSEQ - 1 - (t0 + lr)) : (t0 + lr);
            pz = *(const ushort4*)&zz[((size_t)b * LSEQ + tz) * 2048 + 1024 + d0 + lc4];
        }

#pragma unroll 4
        for (int tt = 0; tt < 64; tt += 4) {
            const float4 d4 = *(const float4*)&sdt[di][tt];
            const float4 x4 = *(const float4*)&sxi[di][tt];
            const float4 b4 = *(const float4*)&sB[n][tt];
            const float4 c4 = *(const float4*)&sC[n][tt];
            {
                h = fmaf(__expf(d4.x * Av), h, (d4.x * x4.x) * b4.x);
                const float pp = row_sum16(h * c4.x);
                if (n == 0) sy[di][tt + 0] = pp;
            }
            {
                h = fmaf(__expf(d4.y * Av), h, (d4.y * x4.y) * b4.y);
                const float pp = row_sum16(h * c4.y);
                if (n == 0) sy[di][tt + 1] = pp;
            }
            {
                h = fmaf(__expf(d4.z * Av), h, (d4.z * x4.z) * b4.z);
                const float pp = row_sum16(h * c4.z);
                if (n == 0) sy[di][tt + 2] = pp;
            }
            {
                h = fmaf(__expf(d4.w * Av), h, (d4.w * x4.w) * b4.w);
                const float pp = row_sum16(h * c4.w);
                if (n == 0) sy[di][tt + 3] = pp;
            }
        }
        __syncthreads();

        const size_t r = (size_t)b * LSEQ + t0 + lr;
        float4 y4, xi4;
        y4.x = sy[lc4 + 0][lr]; y4.y = sy[lc4 + 1][lr]; y4.z = sy[lc4 + 2][lr]; y4.w = sy[lc4 + 3][lr];
        xi4.x = sxi[lc4 + 0][lr]; xi4.y = sxi[lc4 + 1][lr]; xi4.z = sxi[lc4 + 2][lr]; xi4.w = sxi[lc4 + 3][lr];
        ushort4 st;
        st.x = f2bf(fmaf(xi4.x, dpv[0], y4.x) * silu_f(bf2f(pz.x)));
        st.y = f2bf(fmaf(xi4.y, dpv[1], y4.y) * silu_f(bf2f(pz.y)));
        st.z = f2bf(fmaf(xi4.z, dpv[2], y4.z) * silu_f(bf2f(pz.z)));
        st.w = f2bf(fmaf(xi4.w, dpv[3], y4.w) * silu_f(bf2f(pz.w)));
        *(ushort4*)&xiy[r * 1024 + d0 + lc4] = st;
    }
}

// ---------------------------------------------------------------------------
extern "C" void kernel_launch(void* const* d_in, const int* in_sizes, int n_in,
                              void* d_out, int out_size, void* d_ws, size_t ws_size,
                              hipStream_t stream)
{
    const float* x      = (const float*)d_in[0];
    const float* f_in_w = (const float*)d_in[1];
    const float* f_cw   = (const float*)d_in[2];
    const float* f_cb   = (const float*)d_in[3];
    const float* f_xp   = (const float*)d_in[4];
    const float* f_dtw  = (const float*)d_in[5];
    const float* f_dtb  = (const float*)d_in[6];
    const float* f_Al   = (const float*)d_in[7];
    const float* f_Dp   = (const float*)d_in[8];
    const float* f_ow   = (const float*)d_in[9];
    const float* b_in_w = (const float*)d_in[10];
    const float* b_cw   = (const float*)d_in[11];
    const float* b_cb   = (const float*)d_in[12];
    const float* b_xp   = (const float*)d_in[13];
    const float* b_dtw  = (const float*)d_in[14];
    const float* b_dtb  = (const float*)d_in[15];
    const float* b_Al   = (const float*)d_in[16];
    const float* b_Dp   = (const float*)d_in[17];
    const float* b_ow   = (const float*)d_in[18];
    const float* lin_w  = (const float*)d_in[19];
    const float* lin_b  = (const float*)d_in[20];
    float* out = (float*)d_out;

    char* p = (char*)d_ws;
    auto take = [&](size_t bytes) -> char* {
        char* r = p; p += (bytes + 255) & ~(size_t)255; return r;
    };

    // persistent bf16 weights
    unsigned short* wif  = (unsigned short*)take((size_t)2048 * 512 * 2);
    unsigned short* wib  = (unsigned short*)take((size_t)2048 * 512 * 2);
    unsigned short* wxf  = (unsigned short*)take((size_t)64 * 1024 * 2);
    unsigned short* wxb  = (unsigned short*)take((size_t)64 * 1024 * 2);
    unsigned short* wdtf = (unsigned short*)take((size_t)1024 * 32 * 2);
    unsigned short* wdtb = (unsigned short*)take((size_t)1024 * 32 * 2);
    unsigned short* wcmb = (unsigned short*)take((size_t)512 * 2048 * 2);

    const size_t used = (size_t)(p - (char*)d_ws);
    // per-row bytes: xbf 1024 + per dir (xz 4096 + xiy 2048 + dbl 256 + dt 2048)
    const size_t perRow = 1024 + 2 * (4096 + 2048 + 256 + 2048);
    int G = 1;
    for (int g = 8; g >= 1; g >>= 1) {
        const size_t need = used + (size_t)g * LSEQ * perRow + 16384;
        if (need <= ws_size || g == 1) { G = g; break; }
    }

    CvtArgs ca;
    ca.s[0] = f_in_w; ca.d[0] = wif;  ca.n[0] = 2048 * 512;
    ca.s[1] = b_in_w; ca.d[1] = wib;  ca.n[1] = 2048 * 512;
    ca.s[2] = f_xp;   ca.d[2] = wxf;  ca.n[2] = 64 * 1024;
    ca.s[3] = b_xp;   ca.d[3] = wxb;  ca.n[3] = 64 * 1024;
    ca.s[4] = f_dtw;  ca.d[4] = wdtf; ca.n[4] = 1024 * 32;
    ca.s[5] = b_dtw;  ca.d[5] = wdtb; ca.n[5] = 1024 * 32;
    cvt_k<<<dim3(128, 6), 256, 0, stream>>>(ca);

    // combined (lin_w @ out_w) weight, bf16, (512 x 2048)
    combine_k<<<dim3(4, 128, 2), 256, 0, stream>>>(lin_w, f_ow, b_ow, wcmb);

    char* pg0 = p;
    for (int g0 = 0; g0 < NBATCH; g0 += G) {
        const int Mg = G * LSEQ;
        p = pg0;
        unsigned short* xbf   = (unsigned short*)take((size_t)Mg * 512 * 2);
        unsigned short* xz_f  = (unsigned short*)take((size_t)Mg * 2048 * 2);
        unsigned short* xz_b  = (unsigned short*)take((size_t)Mg * 2048 * 2);
        unsigned short* xiy_f = (unsigned short*)take((size_t)Mg * 1024 * 2);
        unsigned short* xiy_b = (unsigned short*)take((size_t)Mg * 1024 * 2);
        float* dbl_f          = (float*)take((size_t)Mg * 64 * 4);
        float* dbl_b          = (float*)take((size_t)Mg * 64 * 4);
        unsigned short* dt_f  = (unsigned short*)take((size_t)Mg * 1024 * 2);
        unsigned short* dt_b  = (unsigned short*)take((size_t)Mg * 1024 * 2);

        const float* xg = x + (size_t)g0 * LSEQ * 512;
        float* outg = out + (size_t)g0 * LSEQ * 512;

        cvtx_k<<<dim3(512), 256, 0, stream>>>(xg, xbf, Mg * 512 / 4);

        GemmPair g1 = {};   // in-proj: xz = x @ in_w^T (N=2048), bf16 out
        g1.A[0] = xbf; g1.A[1] = xbf; g1.W[0] = wif; g1.W[1] = wib;
        g1.C[0] = xz_f; g1.C[1] = xz_b;
        gemm_mfma<2,2,1,0><<<dim3(Mg/128, 16, 2), 256, 0, stream>>>(g1, 512, 512, 2048, 512);

        conv_silu_k<<<dim3(Mg, 2), 256, 0, stream>>>(xz_f, f_cw, f_cb, xiy_f,
                                                     xz_b, b_cw, b_cb, xiy_b);

        XprojPair xpp = {};   // fused x-proj + dt
        xpp.xi[0] = xiy_f; xpp.xi[1] = xiy_b;
        xpp.xpw[0] = wxf;  xpp.xpw[1] = wxb;
        xpp.dtw[0] = wdtf; xpp.dtw[1] = wdtb;
        xpp.dtb[0] = f_dtb; xpp.dtb[1] = b_dtb;
        xpp.dbl[0] = dbl_f; xpp.dbl[1] = dbl_b;
        xpp.dt[0] = dt_f;   xpp.dt[1] = dt_b;
        xproj_dt_k<<<dim3(Mg/128, 1, 2), 256, 0, stream>>>(xpp);

        scan_k<<<dim3(64, G, 2), 256, 0, stream>>>(dt_f, xiy_f, dbl_f, xz_f, f_Al, f_Dp,
                                                   dt_b, xiy_b, dbl_b, xz_b, b_Al, b_Dp);

        // fused out-proj+final: out = [y_f | rev(y_b)] @ Wcomb^T + lin_b  (K=2048)
        GemmPair g5 = {};
        g5.A[0] = xiy_f; g5.A2[0] = xiy_b; g5.W[0] = wcmb;
        g5.bias[0] = lin_b; g5.C[0] = outg;
        gemm_mfma<2,2,0,1><<<dim3(Mg/128, 4, 1), 256, 0, stream>>>(g5, 1024, 2048, 512, 2048);
    }
}

// Round 8
// 1113.493 us; speedup vs baseline: 1.0901x; 1.0901x over previous
//
#include <hip/hip_runtime.h>
#include <cmath>

#define LSEQ 2048
#define NBATCH 8

typedef __attribute__((ext_vector_type(8))) short short8;
typedef __attribute__((ext_vector_type(4))) float f32x4;

__device__ __forceinline__ float silu_f(float x) { return x / (1.0f + __expf(-x)); }
__device__ __forceinline__ float softplus_f(float x) {
    return fmaxf(x, 0.0f) + log1pf(__expf(-fabsf(x)));
}
__device__ __forceinline__ unsigned short f2bf(float f) {   // RNE fp32->bf16
    unsigned int u = __float_as_uint(f);
    u += 0x7FFFu + ((u >> 16) & 1u);
    return (unsigned short)(u >> 16);
}
__device__ __forceinline__ float bf2f(unsigned short h) {
    return __uint_as_float(((unsigned int)h) << 16);
}
__device__ __forceinline__ void gload_lds16(const void* g, void* l) {
    __builtin_amdgcn_global_load_lds((const __attribute__((address_space(1))) void*)g,
                                     (__attribute__((address_space(3))) void*)l, 16, 0, 0);
}

// fwd/bwd operand pairs; blockIdx.z selects direction
struct GemmPair {
    const unsigned short* A[2];
    const unsigned short* A2[2];   // DUAL second A (second K-half, row-reversed)
    const unsigned short* W[2];
    const float* bias[2];
    void* C[2];
    unsigned short* aux[2];
};

// ---------------------------------------------------------------------------
// bf16 MFMA GEMM (NT): C[m,n] = act( A[m,:].W[n,:] + bias[n] )
// WGM x WGN waves; each wave 64x64 via 4x4 mfma_f32_16x16x32_bf16.
// BK = 32 or 64 (BK=64 halves barrier-drain count; LDS 2x).
// blockIdx.x = m-tile (gridDim.x % 8 == 0 keeps same-A blocks on one XCD).
// OMODE: 0=f32, 1=bf16, 2=f32+softplus, 3=bf16+softplus.
// DUAL: k>=512 reads A2 (stride 512) at row^2047. XTRA: bf16 copy of cols<32.
// Scalar epilogue (measured best: r4 = 1030 us vs r7 LDS-staged = +86 us).
// ---------------------------------------------------------------------------
template<int WGM, int WGN, int BK, int OMODE, int DUAL, int XTRA>
__global__ __launch_bounds__(WGM* WGN * 64) void gemm_mfma(GemmPair gp, int lda, int ldw,
                                                           int ldc, int K)
{
    constexpr int NW = WGM * WGN;
    constexpr int TM = WGM * 64, TN = WGN * 64;
    constexpr int LPR = BK / 8;          // lanes per row (16B each)
    constexpr int RPG = 64 / LPR;        // rows per gload (1KB per gload)
    __shared__ unsigned short As[TM * BK];
    __shared__ unsigned short Bs[TN * BK];
    const int dir = blockIdx.z;
    const unsigned short* A  = gp.A[dir];
    const unsigned short* A2 = gp.A2[dir];
    const unsigned short* W  = gp.W[dir];
    const float* bias        = gp.bias[dir];
    void* Cout               = gp.C[dir];
    unsigned short* aux      = gp.aux[dir];

    const int tid = threadIdx.x;
    const int wave = tid >> 6, lane = tid & 63;
    const int wm = wave / WGN, wn = wave % WGN;
    const int m0 = blockIdx.x * TM, n0 = blockIdx.y * TN;
    const int l15 = lane & 15, l4 = lane >> 4;
    const int srow = lane / LPR, schunk = (lane % LPR) * 8;

    f32x4 acc[4][4] = {};

    for (int k0 = 0; k0 < K; k0 += BK) {
        __syncthreads();
        for (int s = wave; s < TM / RPG; s += NW) {
            const int gr = m0 + s * RPG + srow;
            const unsigned short* g;
            if (DUAL && k0 >= 512)
                g = A2 + (size_t)(gr ^ (LSEQ - 1)) * 512 + (k0 - 512) + schunk;
            else
                g = A + (size_t)gr * lda + k0 + schunk;
            gload_lds16(g, (char*)As + (size_t)s * 1024);
        }
        for (int s = wave; s < TN / RPG; s += NW) {
            const int gr = n0 + s * RPG + srow;
            const unsigned short* g = W + (size_t)gr * ldw + k0 + schunk;
            gload_lds16(g, (char*)Bs + (size_t)s * 1024);
        }
        __syncthreads();
#pragma unroll
        for (int kk = 0; kk < BK; kk += 32) {
            short8 af[4], bfr[4];
#pragma unroll
            for (int mi = 0; mi < 4; ++mi)
                af[mi] = *(const short8*)&As[(wm * 64 + mi * 16 + l15) * BK + kk + l4 * 8];
#pragma unroll
            for (int ni = 0; ni < 4; ++ni)
                bfr[ni] = *(const short8*)&Bs[(wn * 64 + ni * 16 + l15) * BK + kk + l4 * 8];
#pragma unroll
            for (int mi = 0; mi < 4; ++mi)
#pragma unroll
                for (int ni = 0; ni < 4; ++ni)
                    acc[mi][ni] = __builtin_amdgcn_mfma_f32_16x16x32_bf16(af[mi], bfr[ni], acc[mi][ni], 0, 0, 0);
        }
    }

#pragma unroll
    for (int mi = 0; mi < 4; ++mi)
#pragma unroll
        for (int ni = 0; ni < 4; ++ni)
#pragma unroll
            for (int r = 0; r < 4; ++r) {
                const int row = m0 + wm * 64 + mi * 16 + l4 * 4 + r;
                const int col = n0 + wn * 64 + ni * 16 + l15;
                float v = acc[mi][ni][r];
                if (bias) v += bias[col];
                if (OMODE >= 2) v = softplus_f(v);
                if (OMODE & 1) ((unsigned short*)Cout)[(size_t)row * ldc + col] = f2bf(v);
                else           ((float*)Cout)[(size_t)row * ldc + col] = v;
                if (XTRA) { if (col < 32) aux[(size_t)row * 32 + col] = f2bf(v); }
            }
}

// ---------------------------------------------------------------------------
// fp32 -> bf16 conversion: 9 weight segments, one launch.
// ---------------------------------------------------------------------------
struct CvtArgs { const float* s[9]; unsigned short* d[9]; int n[9]; };
__global__ __launch_bounds__(256) void cvt_k(CvtArgs a)
{
    const int sid = blockIdx.y;
    const float* s = a.s[sid];
    unsigned short* d = a.d[sid];
    const int n4 = a.n[sid] >> 2;
    for (int i = blockIdx.x * 256 + threadIdx.x; i < n4; i += gridDim.x * 256) {
        const float4 v = ((const float4*)s)[i];
        ushort4 o; o.x = f2bf(v.x); o.y = f2bf(v.y); o.z = f2bf(v.z); o.w = f2bf(v.w);
        ((ushort4*)d)[i] = o;
    }
}
__global__ __launch_bounds__(256) void cvtx_k(const float* __restrict__ s,
                                              unsigned short* __restrict__ d, int n4)
{
    for (int i = blockIdx.x * 256 + threadIdx.x; i < n4; i += gridDim.x * 256) {
        const float4 v = ((const float4*)s)[i];
        ushort4 o; o.x = f2bf(v.x); o.y = f2bf(v.y); o.z = f2bf(v.z); o.w = f2bf(v.w);
        ((ushort4*)d)[i] = o;
    }
}

// ---------------------------------------------------------------------------
// Causal depthwise conv(4) + bias + SiLU, both dirs; bf16 in (xz cols 0..1023,
// ld 2048), bf16 out. Backward dir indexes reversed rows.
// ---------------------------------------------------------------------------
__global__ __launch_bounds__(256) void conv_silu_k(
    const unsigned short* __restrict__ xz_f, const float* __restrict__ cw_f,
    const float* __restrict__ cb_f, unsigned short* __restrict__ xi_f,
    const unsigned short* __restrict__ xz_b, const float* __restrict__ cw_b,
    const float* __restrict__ cb_b, unsigned short* __restrict__ xi_b)
{
    const int dir = blockIdx.y;
    const unsigned short* xz = dir ? xz_b : xz_f;
    const float* cw = dir ? cw_b : cw_f;
    const float* cb = dir ? cb_b : cb_f;
    unsigned short* xi = dir ? xi_b : xi_f;

    const int bt = blockIdx.x;
    const int b = bt >> 11;
    const int t = bt & (LSEQ - 1);
    const int d = threadIdx.x << 2;

    float w[4][4];
#pragma unroll
    for (int i = 0; i < 4; ++i) {
        const float4 wr = *(const float4*)&cw[(d + i) * 4];
        w[i][0] = wr.x; w[i][1] = wr.y; w[i][2] = wr.z; w[i][3] = wr.w;
    }
    float4 acc = *(const float4*)&cb[d];
#pragma unroll
    for (int k = 0; k < 4; ++k) {
        const int row = dir ? (LSEQ - 1 - t) + 3 - k : t - 3 + k;
        if ((unsigned)row < (unsigned)LSEQ) {
            const ushort4 v = *(const ushort4*)&xz[(size_t)(b * LSEQ + row) * 2048 + d];
            acc.x += w[0][k] * bf2f(v.x); acc.y += w[1][k] * bf2f(v.y);
            acc.z += w[2][k] * bf2f(v.z); acc.w += w[3][k] * bf2f(v.w);
        }
    }
    ushort4 st;
    st.x = f2bf(silu_f(acc.x)); st.y = f2bf(silu_f(acc.y));
    st.z = f2bf(silu_f(acc.z)); st.w = f2bf(silu_f(acc.w));
    *(ushort4*)&xi[(size_t)(b * LSEQ + t) * 1024 + d] = st;
}

// ---------------------------------------------------------------------------
// Selective scan (r4/r6 16ch x 16state layout, LDS [ch][t], DPP 16-lane
// reduce, register prefetch). New: u = dt*xi precomputed at staging (su),
// removing one mul from the serial inner loop. Writes gated y bf16 over xi.
// ---------------------------------------------------------------------------
__device__ __forceinline__ float row_sum16(float x) {
    x += __int_as_float(__builtin_amdgcn_update_dpp(0, __float_as_int(x), 0xB1, 0xF, 0xF, false));  // quad xor1
    x += __int_as_float(__builtin_amdgcn_update_dpp(0, __float_as_int(x), 0x4E, 0xF, 0xF, false));  // quad xor2
    x += __int_as_float(__builtin_amdgcn_update_dpp(0, __float_as_int(x), 0x141, 0xF, 0xF, false)); // row_half_mirror
    x += __int_as_float(__builtin_amdgcn_update_dpp(0, __float_as_int(x), 0x140, 0xF, 0xF, false)); // row_mirror
    return x;
}

__global__ __launch_bounds__(256) void scan_k(
    const unsigned short* __restrict__ dt_f, unsigned short* __restrict__ xiy_f,
    const float* __restrict__ dbl_f, const unsigned short* __restrict__ xz_f,
    const float* __restrict__ Al_f, const float* __restrict__ Dp_f,
    const unsigned short* __restrict__ dt_b, unsigned short* __restrict__ xiy_b,
    const float* __restrict__ dbl_b, const unsigned short* __restrict__ xz_b,
    const float* __restrict__ Al_b, const float* __restrict__ Dp_b)
{
    __shared__ float sdt[16][68], su[16][68], sxi[16][68], sB[16][68], sC[16][68], sy[16][68];

    const int dir = blockIdx.z;
    const unsigned short* dt = dir ? dt_b : dt_f;
    unsigned short* xiy = dir ? xiy_b : xiy_f;
    const float* dbl = dir ? dbl_b : dbl_f;
    const unsigned short* zz = dir ? xz_b : xz_f;
    const float* Al = dir ? Al_b : Al_f;
    const float* Dpp = dir ? Dp_b : Dp_f;

    const int b = blockIdx.y, d0 = blockIdx.x << 4;
    const int tid = threadIdx.x;
    const int di = tid >> 4, n = tid & 15;
    const float Av = -expf(Al[(d0 + di) * 16 + n]);
    const int lr = tid >> 2, lc4 = (tid & 3) << 2;
    float dpv[4];
#pragma unroll
    for (int i = 0; i < 4; ++i) dpv[i] = Dpp[d0 + lc4 + i];

    ushort4 pdt, pxi, pz;
    float4 pB, pC;
    auto issue_loads = [&](int c) {
        const size_t r = (size_t)b * LSEQ + c * 64 + lr;
        pdt = *(const ushort4*)&dt[r * 1024 + d0 + lc4];
        pxi = *(const ushort4*)&xiy[r * 1024 + d0 + lc4];
        pB  = *(const float4*)&dbl[r * 64 + 32 + lc4];
        pC  = *(const float4*)&dbl[r * 64 + 48 + lc4];
    };
    issue_loads(0);

    float h = 0.0f;
    for (int c = 0; c < LSEQ / 64; ++c) {
        const int t0 = c * 64;
        __syncthreads();
        {
            const float d0v = bf2f(pdt.x), d1v = bf2f(pdt.y), d2v = bf2f(pdt.z), d3v = bf2f(pdt.w);
            const float x0v = bf2f(pxi.x), x1v = bf2f(pxi.y), x2v = bf2f(pxi.z), x3v = bf2f(pxi.w);
            sdt[lc4 + 0][lr] = d0v; sdt[lc4 + 1][lr] = d1v; sdt[lc4 + 2][lr] = d2v; sdt[lc4 + 3][lr] = d3v;
            su[lc4 + 0][lr] = d0v * x0v; su[lc4 + 1][lr] = d1v * x1v;
            su[lc4 + 2][lr] = d2v * x2v; su[lc4 + 3][lr] = d3v * x3v;
            sxi[lc4 + 0][lr] = x0v; sxi[lc4 + 1][lr] = x1v;
            sxi[lc4 + 2][lr] = x2v; sxi[lc4 + 3][lr] = x3v;
            sB[lc4 + 0][lr] = pB.x; sB[lc4 + 1][lr] = pB.y; sB[lc4 + 2][lr] = pB.z; sB[lc4 + 3][lr] = pB.w;
            sC[lc4 + 0][lr] = pC.x; sC[lc4 + 1][lr] = pC.y; sC[lc4 + 2][lr] = pC.z; sC[lc4 + 3][lr] = pC.w;
        }
        __syncthreads();

        if (c + 1 < LSEQ / 64) issue_loads(c + 1);
        {
            const int tz = dir ? (LSEQ - 1 - (t0 + lr)) : (t0 + lr);
            pz = *(const ushort4*)&zz[((size_t)b * LSEQ + tz) * 2048 + 1024 + d0 + lc4];
        }

#pragma unroll 4
        for (int tt = 0; tt < 64; tt += 4) {
            const float4 d4 = *(const float4*)&sdt[di][tt];
            const float4 u4 = *(const float4*)&su[di][tt];
            const float4 b4 = *(const float4*)&sB[n][tt];
            const float4 c4 = *(const float4*)&sC[n][tt];
            {
                h = fmaf(__expf(d4.x * Av), h, u4.x * b4.x);
                const float pp = row_sum16(h * c4.x);
                if (n == 0) sy[di][tt + 0] = pp;
            }
            {
                h = fmaf(__expf(d4.y * Av), h, u4.y * b4.y);
                const float pp = row_sum16(h * c4.y);
                if (n == 0) sy[di][tt + 1] = pp;
            }
            {
                h = fmaf(__expf(d4.z * Av), h, u4.z * b4.z);
                const float pp = row_sum16(h * c4.z);
                if (n == 0) sy[di][tt + 2] = pp;
            }
            {
                h = fmaf(__expf(d4.w * Av), h, u4.w * b4.w);
                const float pp = row_sum16(h * c4.w);
                if (n == 0) sy[di][tt + 3] = pp;
            }
        }
        __syncthreads();

        const size_t r = (size_t)b * LSEQ + t0 + lr;
        float4 y4, xi4;
        y4.x = sy[lc4 + 0][lr]; y4.y = sy[lc4 + 1][lr]; y4.z = sy[lc4 + 2][lr]; y4.w = sy[lc4 + 3][lr];
        xi4.x = sxi[lc4 + 0][lr]; xi4.y = sxi[lc4 + 1][lr]; xi4.z = sxi[lc4 + 2][lr]; xi4.w = sxi[lc4 + 3][lr];
        ushort4 st;
        st.x = f2bf(fmaf(xi4.x, dpv[0], y4.x) * silu_f(bf2f(pz.x)));
        st.y = f2bf(fmaf(xi4.y, dpv[1], y4.y) * silu_f(bf2f(pz.y)));
        st.z = f2bf(fmaf(xi4.z, dpv[2], y4.z) * silu_f(bf2f(pz.z)));
        st.w = f2bf(fmaf(xi4.w, dpv[3], y4.w) * silu_f(bf2f(pz.w)));
        *(ushort4*)&xiy[r * 1024 + d0 + lc4] = st;
    }
}

// ---------------------------------------------------------------------------
extern "C" void kernel_launch(void* const* d_in, const int* in_sizes, int n_in,
                              void* d_out, int out_size, void* d_ws, size_t ws_size,
                              hipStream_t stream)
{
    const float* x      = (const float*)d_in[0];
    const float* f_in_w = (const float*)d_in[1];
    const float* f_cw   = (const float*)d_in[2];
    const float* f_cb   = (const float*)d_in[3];
    const float* f_xp   = (const float*)d_in[4];
    const float* f_dtw  = (const float*)d_in[5];
    const float* f_dtb  = (const float*)d_in[6];
    const float* f_Al   = (const float*)d_in[7];
    const float* f_Dp   = (const float*)d_in[8];
    const float* f_ow   = (const float*)d_in[9];
    const float* b_in_w = (const float*)d_in[10];
    const float* b_cw   = (const float*)d_in[11];
    const float* b_cb   = (const float*)d_in[12];
    const float* b_xp   = (const float*)d_in[13];
    const float* b_dtw  = (const float*)d_in[14];
    const float* b_dtb  = (const float*)d_in[15];
    const float* b_Al   = (const float*)d_in[16];
    const float* b_Dp   = (const float*)d_in[17];
    const float* b_ow   = (const float*)d_in[18];
    const float* lin_w  = (const float*)d_in[19];
    const float* lin_b  = (const float*)d_in[20];
    float* out = (float*)d_out;

    char* p = (char*)d_ws;
    auto take = [&](size_t bytes) -> char* {
        char* r = p; p += (bytes + 255) & ~(size_t)255; return r;
    };

    // persistent bf16 weights
    unsigned short* wif  = (unsigned short*)take((size_t)2048 * 512 * 2);
    unsigned short* wib  = (unsigned short*)take((size_t)2048 * 512 * 2);
    unsigned short* wxf  = (unsigned short*)take((size_t)64 * 1024 * 2);
    unsigned short* wxb  = (unsigned short*)take((size_t)64 * 1024 * 2);
    unsigned short* wof  = (unsigned short*)take((size_t)512 * 1024 * 2);
    unsigned short* wob  = (unsigned short*)take((size_t)512 * 1024 * 2);
    unsigned short* wlin = (unsigned short*)take((size_t)512 * 1024 * 2);
    unsigned short* wdtf = (unsigned short*)take((size_t)1024 * 32 * 2);
    unsigned short* wdtb = (unsigned short*)take((size_t)1024 * 32 * 2);

    const size_t used = (size_t)(p - (char*)d_ws);
    // per-row bytes: xbf 1024 + per dir (xz 4096 + xiy 2048 + dbl 256 + dblh 64 + dt 2048 + o 1024)
    const size_t perRow = 1024 + 2 * (4096 + 2048 + 256 + 64 + 2048 + 1024);
    int G = 1;
    for (int g = 8; g >= 1; g >>= 1) {
        const size_t need = used + (size_t)g * LSEQ * perRow + 16384;
        if (need <= ws_size || g == 1) { G = g; break; }
    }

    CvtArgs ca;
    ca.s[0] = f_in_w; ca.d[0] = wif;  ca.n[0] = 2048 * 512;
    ca.s[1] = b_in_w; ca.d[1] = wib;  ca.n[1] = 2048 * 512;
    ca.s[2] = f_xp;   ca.d[2] = wxf;  ca.n[2] = 64 * 1024;
    ca.s[3] = b_xp;   ca.d[3] = wxb;  ca.n[3] = 64 * 1024;
    ca.s[4] = f_ow;   ca.d[4] = wof;  ca.n[4] = 512 * 1024;
    ca.s[5] = b_ow;   ca.d[5] = wob;  ca.n[5] = 512 * 1024;
    ca.s[6] = lin_w;  ca.d[6] = wlin; ca.n[6] = 512 * 1024;
    ca.s[7] = f_dtw;  ca.d[7] = wdtf; ca.n[7] = 1024 * 32;
    ca.s[8] = b_dtw;  ca.d[8] = wdtb; ca.n[8] = 1024 * 32;
    cvt_k<<<dim3(256, 9), 256, 0, stream>>>(ca);

    char* pg0 = p;
    for (int g0 = 0; g0 < NBATCH; g0 += G) {
        const int Mg = G * LSEQ;
        p = pg0;
        unsigned short* xbf   = (unsigned short*)take((size_t)Mg * 512 * 2);
        unsigned short* xz_f  = (unsigned short*)take((size_t)Mg * 2048 * 2);
        unsigned short* xz_b  = (unsigned short*)take((size_t)Mg * 2048 * 2);
        unsigned short* xiy_f = (unsigned short*)take((size_t)Mg * 1024 * 2);
        unsigned short* xiy_b = (unsigned short*)take((size_t)Mg * 1024 * 2);
        float* dbl_f          = (float*)take((size_t)Mg * 64 * 4);
        float* dbl_b          = (float*)take((size_t)Mg * 64 * 4);
        unsigned short* dblh_f= (unsigned short*)take((size_t)Mg * 32 * 2);
        unsigned short* dblh_b= (unsigned short*)take((size_t)Mg * 32 * 2);
        unsigned short* dt_f  = (unsigned short*)take((size_t)Mg * 1024 * 2);
        unsigned short* dt_b  = (unsigned short*)take((size_t)Mg * 1024 * 2);
        unsigned short* o_f   = (unsigned short*)take((size_t)Mg * 512 * 2);
        unsigned short* o_b   = (unsigned short*)take((size_t)Mg * 512 * 2);

        const float* xg = x + (size_t)g0 * LSEQ * 512;
        float* outg = out + (size_t)g0 * LSEQ * 512;

        cvtx_k<<<dim3(512), 256, 0, stream>>>(xg, xbf, Mg * 512 / 4);

        GemmPair g1 = {};   // in-proj: xz = x @ in_w^T (N=2048), bf16 out, BK=64
        g1.A[0] = xbf; g1.A[1] = xbf; g1.W[0] = wif; g1.W[1] = wib;
        g1.C[0] = xz_f; g1.C[1] = xz_b;
        gemm_mfma<2,2,64,1,0,0><<<dim3(Mg/128, 16, 2), 256, 0, stream>>>(g1, 512, 512, 2048, 512);

        conv_silu_k<<<dim3(Mg, 2), 256, 0, stream>>>(xz_f, f_cw, f_cb, xiy_f,
                                                     xz_b, b_cw, b_cb, xiy_b);

        GemmPair g2 = {};   // x-proj: dbl f32 (ldc 64) + bf16 cols<32 (dblh); 128-thr, 256 blocks
        g2.A[0] = xiy_f; g2.A[1] = xiy_b; g2.W[0] = wxf; g2.W[1] = wxb;
        g2.C[0] = dbl_f; g2.C[1] = dbl_b; g2.aux[0] = dblh_f; g2.aux[1] = dblh_b;
        gemm_mfma<2,1,32,0,0,1><<<dim3(Mg/128, 1, 2), 128, 0, stream>>>(g2, 1024, 1024, 64, 1024);

        GemmPair g3 = {};   // dt = softplus(dblh @ dt_w^T + dt_b), bf16 out, BK=32 (K=32)
        g3.A[0] = dblh_f; g3.A[1] = dblh_b; g3.W[0] = wdtf; g3.W[1] = wdtb;
        g3.bias[0] = f_dtb; g3.bias[1] = b_dtb; g3.C[0] = dt_f; g3.C[1] = dt_b;
        gemm_mfma<2,2,32,3,0,0><<<dim3(Mg/128, 8, 2), 256, 0, stream>>>(g3, 32, 32, 1024, 32);

        scan_k<<<dim3(64, G, 2), 256, 0, stream>>>(dt_f, xiy_f, dbl_f, xz_f, f_Al, f_Dp,
                                                   dt_b, xiy_b, dbl_b, xz_b, b_Al, b_Dp);

        GemmPair g4 = {};   // out-proj: o = y @ out_w^T, bf16 out, BK=64
        g4.A[0] = xiy_f; g4.A[1] = xiy_b; g4.W[0] = wof; g4.W[1] = wob;
        g4.C[0] = o_f; g4.C[1] = o_b;
        gemm_mfma<2,2,64,1,0,0><<<dim3(Mg/128, 4, 2), 256, 0, stream>>>(g4, 1024, 1024, 512, 1024);

        GemmPair g5 = {};   // final: out = [o_f | rev(o_b)] @ lin_w^T + lin_b, f32, BK=64 DUAL
        g5.A[0] = o_f; g5.A2[0] = o_b; g5.W[0] = wlin; g5.bias[0] = lin_b; g5.C[0] = outg;
        gemm_mfma<2,2,64,0,1,0><<<dim3(Mg/128, 4, 1), 256, 0, stream>>>(g5, 512, 1024, 512, 1024);
    }
}

// Round 9
// 860.543 us; speedup vs baseline: 1.4105x; 1.2939x over previous
//
#include <hip/hip_runtime.h>
#include <cmath>

#define LSEQ 2048
#define NBATCH 8

typedef __attribute__((ext_vector_type(8))) short short8;
typedef __attribute__((ext_vector_type(4))) float f32x4;

__device__ __forceinline__ float silu_f(float x) { return x / (1.0f + __expf(-x)); }
__device__ __forceinline__ float softplus_f(float x) {
    return fmaxf(x, 0.0f) + log1pf(__expf(-fabsf(x)));
}
__device__ __forceinline__ unsigned short f2bf(float f) {   // RNE fp32->bf16
    unsigned int u = __float_as_uint(f);
    u += 0x7FFFu + ((u >> 16) & 1u);
    return (unsigned short)(u >> 16);
}
__device__ __forceinline__ float bf2f(unsigned short h) {
    return __uint_as_float(((unsigned int)h) << 16);
}
__device__ __forceinline__ void gload_lds16(const void* g, void* l) {
    __builtin_amdgcn_global_load_lds((const __attribute__((address_space(1))) void*)g,
                                     (__attribute__((address_space(3))) void*)l, 16, 0, 0);
}

// fwd/bwd operand pairs; blockIdx.z selects direction
struct GemmPair {
    const unsigned short* A[2];
    const unsigned short* A2[2];   // DUAL second A (second K-half, row-reversed)
    const unsigned short* W[2];
    const float* bias[2];
    void* C[2];
    unsigned short* aux[2];
};

// ---------------------------------------------------------------------------
// bf16 MFMA GEMM (NT), r4-proven config: BK=32, scalar epilogue.
// WGM x WGN waves; each wave 64x64 via 4x4 mfma_f32_16x16x32_bf16.
// blockIdx.x = m-tile (gridDim.x % 8 == 0 keeps same-A blocks on one XCD).
// OMODE: 0=f32, 1=bf16. DK: k0>=DK reads A2 (stride lda) at row^2047.
// XTRA: bf16 copy of cols<32 to aux.
// ---------------------------------------------------------------------------
template<int WGM, int WGN, int OMODE, int DK, int XTRA>
__global__ __launch_bounds__(WGM* WGN * 64) void gemm_mfma(GemmPair gp, int lda, int ldw,
                                                           int ldc, int K)
{
    constexpr int NW = WGM * WGN;
    constexpr int TM = WGM * 64, TN = WGN * 64;
    __shared__ unsigned short As[TM * 32];
    __shared__ unsigned short Bs[TN * 32];
    const int dir = blockIdx.z;
    const unsigned short* A  = gp.A[dir];
    const unsigned short* A2 = gp.A2[dir];
    const unsigned short* W  = gp.W[dir];
    const float* bias        = gp.bias[dir];
    void* Cout               = gp.C[dir];
    unsigned short* aux      = gp.aux[dir];

    const int tid = threadIdx.x;
    const int wave = tid >> 6, lane = tid & 63;
    const int wm = wave / WGN, wn = wave % WGN;
    const int m0 = blockIdx.x * TM, n0 = blockIdx.y * TN;
    const int l15 = lane & 15, l4 = lane >> 4;
    const int srow = lane >> 2, schunk = (lane & 3) * 8;

    f32x4 acc[4][4] = {};

    for (int k0 = 0; k0 < K; k0 += 32) {
        __syncthreads();
        for (int s = wave; s < TM / 16; s += NW) {
            const int gr = m0 + s * 16 + srow;
            const unsigned short* g;
            if (DK != 0 && k0 >= DK)
                g = A2 + (size_t)(gr ^ (LSEQ - 1)) * lda + (k0 - DK) + schunk;
            else
                g = A + (size_t)gr * lda + k0 + schunk;
            gload_lds16(g, (char*)As + (size_t)s * 1024);
        }
        for (int s = wave; s < TN / 16; s += NW) {
            const int gr = n0 + s * 16 + srow;
            const unsigned short* g = W + (size_t)gr * ldw + k0 + schunk;
            gload_lds16(g, (char*)Bs + (size_t)s * 1024);
        }
        __syncthreads();
        short8 af[4], bfr[4];
#pragma unroll
        for (int mi = 0; mi < 4; ++mi)
            af[mi] = *(const short8*)&As[(wm * 64 + mi * 16 + l15) * 32 + l4 * 8];
#pragma unroll
        for (int ni = 0; ni < 4; ++ni)
            bfr[ni] = *(const short8*)&Bs[(wn * 64 + ni * 16 + l15) * 32 + l4 * 8];
#pragma unroll
        for (int mi = 0; mi < 4; ++mi)
#pragma unroll
            for (int ni = 0; ni < 4; ++ni)
                acc[mi][ni] = __builtin_amdgcn_mfma_f32_16x16x32_bf16(af[mi], bfr[ni], acc[mi][ni], 0, 0, 0);
    }

#pragma unroll
    for (int mi = 0; mi < 4; ++mi)
#pragma unroll
        for (int ni = 0; ni < 4; ++ni)
#pragma unroll
            for (int r = 0; r < 4; ++r) {
                const int row = m0 + wm * 64 + mi * 16 + l4 * 4 + r;
                const int col = n0 + wn * 64 + ni * 16 + l15;
                float v = acc[mi][ni][r];
                if (bias) v += bias[col];
                if (OMODE & 1) ((unsigned short*)Cout)[(size_t)row * ldc + col] = f2bf(v);
                else           ((float*)Cout)[(size_t)row * ldc + col] = v;
                if (XTRA) { if (col < 32) aux[(size_t)row * 32 + col] = f2bf(v); }
            }
}

// ---------------------------------------------------------------------------
// Combined weight for fused out-proj+final (proven r7: identical absmax):
// Wcomb[n, d + dir*1024] = sum_j lin_w[n, j + dir*512] * ow_dir[j, d]  (bf16)
// ---------------------------------------------------------------------------
__global__ __launch_bounds__(256) void combine_k(
    const float* __restrict__ lin_w, const float* __restrict__ owf,
    const float* __restrict__ owb, unsigned short* __restrict__ Wcomb)
{
    const int dir = blockIdx.z;
    const float* ow = dir ? owb : owf;
    const int lane = threadIdx.x & 63;
    const int wave = threadIdx.x >> 6;
    const int n = blockIdx.y * 4 + wave;          // 0..511
    const int d = blockIdx.x * 256 + lane * 4;    // 0..1023
    float4 acc = {0.f, 0.f, 0.f, 0.f};
    const float* lrow = lin_w + (size_t)n * 1024 + dir * 512;
    for (int j = 0; j < 512; ++j) {
        const float s = lrow[j];
        const float4 v = *(const float4*)&ow[(size_t)j * 1024 + d];
        acc.x = fmaf(s, v.x, acc.x); acc.y = fmaf(s, v.y, acc.y);
        acc.z = fmaf(s, v.z, acc.z); acc.w = fmaf(s, v.w, acc.w);
    }
    ushort4 o;
    o.x = f2bf(acc.x); o.y = f2bf(acc.y); o.z = f2bf(acc.z); o.w = f2bf(acc.w);
    *(ushort4*)&Wcomb[(size_t)n * 2048 + dir * 1024 + d] = o;
}

// ---------------------------------------------------------------------------
// fp32 -> bf16 conversion: 6 weight segments, one launch.
// ---------------------------------------------------------------------------
struct CvtArgs { const float* s[6]; unsigned short* d[6]; int n[6]; };
__global__ __launch_bounds__(256) void cvt_k(CvtArgs a)
{
    const int sid = blockIdx.y;
    const float* s = a.s[sid];
    unsigned short* d = a.d[sid];
    const int n4 = a.n[sid] >> 2;
    for (int i = blockIdx.x * 256 + threadIdx.x; i < n4; i += gridDim.x * 256) {
        const float4 v = ((const float4*)s)[i];
        ushort4 o; o.x = f2bf(v.x); o.y = f2bf(v.y); o.z = f2bf(v.z); o.w = f2bf(v.w);
        ((ushort4*)d)[i] = o;
    }
}
__global__ __launch_bounds__(256) void cvtx_k(const float* __restrict__ s,
                                              unsigned short* __restrict__ d, int n4)
{
    for (int i = blockIdx.x * 256 + threadIdx.x; i < n4; i += gridDim.x * 256) {
        const float4 v = ((const float4*)s)[i];
        ushort4 o; o.x = f2bf(v.x); o.y = f2bf(v.y); o.z = f2bf(v.z); o.w = f2bf(v.w);
        ((ushort4*)d)[i] = o;
    }
}

// ---------------------------------------------------------------------------
// Causal depthwise conv(4) + bias + SiLU, both dirs; bf16 in (xz cols 0..1023,
// ld 2048), bf16 out. Backward dir indexes reversed rows.
// ---------------------------------------------------------------------------
__global__ __launch_bounds__(256) void conv_silu_k(
    const unsigned short* __restrict__ xz_f, const float* __restrict__ cw_f,
    const float* __restrict__ cb_f, unsigned short* __restrict__ xi_f,
    const unsigned short* __restrict__ xz_b, const float* __restrict__ cw_b,
    const float* __restrict__ cb_b, unsigned short* __restrict__ xi_b)
{
    const int dir = blockIdx.y;
    const unsigned short* xz = dir ? xz_b : xz_f;
    const float* cw = dir ? cw_b : cw_f;
    const float* cb = dir ? cb_b : cb_f;
    unsigned short* xi = dir ? xi_b : xi_f;

    const int bt = blockIdx.x;
    const int b = bt >> 11;
    const int t = bt & (LSEQ - 1);
    const int d = threadIdx.x << 2;

    float w[4][4];
#pragma unroll
    for (int i = 0; i < 4; ++i) {
        const float4 wr = *(const float4*)&cw[(d + i) * 4];
        w[i][0] = wr.x; w[i][1] = wr.y; w[i][2] = wr.z; w[i][3] = wr.w;
    }
    float4 acc = *(const float4*)&cb[d];
#pragma unroll
    for (int k = 0; k < 4; ++k) {
        const int row = dir ? (LSEQ - 1 - t) + 3 - k : t - 3 + k;
        if ((unsigned)row < (unsigned)LSEQ) {
            const ushort4 v = *(const ushort4*)&xz[(size_t)(b * LSEQ + row) * 2048 + d];
            acc.x += w[0][k] * bf2f(v.x); acc.y += w[1][k] * bf2f(v.y);
            acc.z += w[2][k] * bf2f(v.z); acc.w += w[3][k] * bf2f(v.w);
        }
    }
    ushort4 st;
    st.x = f2bf(silu_f(acc.x)); st.y = f2bf(silu_f(acc.y));
    st.z = f2bf(silu_f(acc.z)); st.w = f2bf(silu_f(acc.w));
    *(ushort4*)&xi[(size_t)(b * LSEQ + t) * 1024 + d] = st;
}

// ---------------------------------------------------------------------------
// Selective scan with IN-KERNEL dt: per 64-t chunk each of the 4 waves runs
// ONE mfma_f32_16x16x32_bf16 (A = dblh rows for its 16 timesteps, B = dtw
// rows for the block's 16 channels), adds dtb, softplus, writes sdt[ch][t]
// (C layout: ch=lane&15, t=w*16+quad*4+r -> float4 in t). Rest = r4/r6
// structure: 16ch x 16state lanes, LDS [ch][t], DPP 16-lane reduce, register
// prefetch. Writes gated y bf16 in place over xi.
// ---------------------------------------------------------------------------
__device__ __forceinline__ float row_sum16(float x) {
    x += __int_as_float(__builtin_amdgcn_update_dpp(0, __float_as_int(x), 0xB1, 0xF, 0xF, false));  // quad xor1
    x += __int_as_float(__builtin_amdgcn_update_dpp(0, __float_as_int(x), 0x4E, 0xF, 0xF, false));  // quad xor2
    x += __int_as_float(__builtin_amdgcn_update_dpp(0, __float_as_int(x), 0x141, 0xF, 0xF, false)); // row_half_mirror
    x += __int_as_float(__builtin_amdgcn_update_dpp(0, __float_as_int(x), 0x140, 0xF, 0xF, false)); // row_mirror
    return x;
}

struct ScanPair {
    const unsigned short* dblh[2];   // (rows x 32) bf16
    const unsigned short* dtw[2];    // (1024 x 32) bf16
    const float* dtb[2];             // (1024) f32
    unsigned short* xiy[2];          // (rows x 1024) bf16, in/out
    const float* dbl[2];             // (rows x 64) f32, B/C in cols 32..63
    const unsigned short* xz[2];     // (rows x 2048) bf16, z in cols 1024+
    const float* Al[2];
    const float* Dp[2];
};

__global__ __launch_bounds__(256) void scan_k(ScanPair sp)
{
    __shared__ float sdt[16][68], sxi[16][68], sB[16][68], sC[16][68], sy[16][68];

    const int dir = blockIdx.z;
    const unsigned short* dblh = sp.dblh[dir];
    const unsigned short* dtw  = sp.dtw[dir];
    const float* dtb           = sp.dtb[dir];
    unsigned short* xiy        = sp.xiy[dir];
    const float* dbl           = sp.dbl[dir];
    const unsigned short* zz   = sp.xz[dir];
    const float* Al            = sp.Al[dir];
    const float* Dpp           = sp.Dp[dir];

    const int b = blockIdx.y, d0 = blockIdx.x << 4;
    const int tid = threadIdx.x;
    const int wave = tid >> 6, lane = tid & 63;
    const int l15 = lane & 15, l4 = lane >> 4;
    const int di = tid >> 4, n = tid & 15;
    const float Av = -expf(Al[(d0 + di) * 16 + n]);
    const int lr = tid >> 2, lc4 = (tid & 3) << 2;
    float dpv[4];
#pragma unroll
    for (int i = 0; i < 4; ++i) dpv[i] = Dpp[d0 + lc4 + i];

    // dt MFMA B-fragment: dtw rows = block channels, resident in regs
    const short8 dtwf = *(const short8*)&dtw[(size_t)(d0 + l15) * 32 + l4 * 8];
    const float dtbv = dtb[d0 + l15];

    ushort4 pxi, pz;
    float4 pB, pC;
    short8 pA;
    auto issue_loads = [&](int c) {
        const size_t r = (size_t)b * LSEQ + c * 64 + lr;
        pxi = *(const ushort4*)&xiy[r * 1024 + d0 + lc4];
        pB  = *(const float4*)&dbl[r * 64 + 32 + lc4];
        pC  = *(const float4*)&dbl[r * 64 + 48 + lc4];
        // dt MFMA A-fragment: rows = this wave's 16 timesteps of the chunk
        pA  = *(const short8*)&dblh[(size_t)(b * LSEQ + c * 64 + wave * 16 + l15) * 32 + l4 * 8];
    };
    issue_loads(0);

    float h = 0.0f;
    for (int c = 0; c < LSEQ / 64; ++c) {
        const int t0 = c * 64;
        __syncthreads();
        sxi[lc4 + 0][lr] = bf2f(pxi.x); sxi[lc4 + 1][lr] = bf2f(pxi.y);
        sxi[lc4 + 2][lr] = bf2f(pxi.z); sxi[lc4 + 3][lr] = bf2f(pxi.w);
        sB[lc4 + 0][lr] = pB.x; sB[lc4 + 1][lr] = pB.y; sB[lc4 + 2][lr] = pB.z; sB[lc4 + 3][lr] = pB.w;
        sC[lc4 + 0][lr] = pC.x; sC[lc4 + 1][lr] = pC.y; sC[lc4 + 2][lr] = pC.z; sC[lc4 + 3][lr] = pC.w;
        {   // dt for this chunk: one MFMA per wave (wave w covers t = w*16..w*16+15)
            f32x4 dacc = {0.f, 0.f, 0.f, 0.f};
            dacc = __builtin_amdgcn_mfma_f32_16x16x32_bf16(pA, dtwf, dacc, 0, 0, 0);
            float4 dv;
            dv.x = softplus_f(dacc[0] + dtbv);
            dv.y = softplus_f(dacc[1] + dtbv);
            dv.z = softplus_f(dacc[2] + dtbv);
            dv.w = softplus_f(dacc[3] + dtbv);
            *(float4*)&sdt[l15][wave * 16 + l4 * 4] = dv;
        }
        __syncthreads();

        if (c + 1 < LSEQ / 64) issue_loads(c + 1);
        {
            const int tz = dir ? (LSEQ - 1 - (t0 + lr)) : (t0 + lr);
            pz = *(const ushort4*)&zz[((size_t)b * LSEQ + tz) * 2048 + 1024 + d0 + lc4];
        }

#pragma unroll 4
        for (int tt = 0; tt < 64; tt += 4) {
            const float4 d4 = *(const float4*)&sdt[di][tt];
            const float4 x4 = *(const float4*)&sxi[di][tt];
            const float4 b4 = *(const float4*)&sB[n][tt];
            const float4 c4 = *(const float4*)&sC[n][tt];
            {
                h = fmaf(__expf(d4.x * Av), h, (d4.x * x4.x) * b4.x);
                const float pp = row_sum16(h * c4.x);
                if (n == 0) sy[di][tt + 0] = pp;
            }
            {
                h = fmaf(__expf(d4.y * Av), h, (d4.y * x4.y) * b4.y);
                const float pp = row_sum16(h * c4.y);
                if (n == 0) sy[di][tt + 1] = pp;
            }
            {
                h = fmaf(__expf(d4.z * Av), h, (d4.z * x4.z) * b4.z);
                const float pp = row_sum16(h * c4.z);
                if (n == 0) sy[di][tt + 2] = pp;
            }
            {
                h = fmaf(__expf(d4.w * Av), h, (d4.w * x4.w) * b4.w);
                const float pp = row_sum16(h * c4.w);
                if (n == 0) sy[di][tt + 3] = pp;
            }
        }
        __syncthreads();

        const size_t r = (size_t)b * LSEQ + t0 + lr;
        float4 y4, xi4;
        y4.x = sy[lc4 + 0][lr]; y4.y = sy[lc4 + 1][lr]; y4.z = sy[lc4 + 2][lr]; y4.w = sy[lc4 + 3][lr];
        xi4.x = sxi[lc4 + 0][lr]; xi4.y = sxi[lc4 + 1][lr]; xi4.z = sxi[lc4 + 2][lr]; xi4.w = sxi[lc4 + 3][lr];
        ushort4 st;
        st.x = f2bf(fmaf(xi4.x, dpv[0], y4.x) * silu_f(bf2f(pz.x)));
        st.y = f2bf(fmaf(xi4.y, dpv[1], y4.y) * silu_f(bf2f(pz.y)));
        st.z = f2bf(fmaf(xi4.z, dpv[2], y4.z) * silu_f(bf2f(pz.z)));
        st.w = f2bf(fmaf(xi4.w, dpv[3], y4.w) * silu_f(bf2f(pz.w)));
        *(ushort4*)&xiy[r * 1024 + d0 + lc4] = st;
    }
}

// ---------------------------------------------------------------------------
extern "C" void kernel_launch(void* const* d_in, const int* in_sizes, int n_in,
                              void* d_out, int out_size, void* d_ws, size_t ws_size,
                              hipStream_t stream)
{
    const float* x      = (const float*)d_in[0];
    const float* f_in_w = (const float*)d_in[1];
    const float* f_cw   = (const float*)d_in[2];
    const float* f_cb   = (const float*)d_in[3];
    const float* f_xp   = (const float*)d_in[4];
    const float* f_dtw  = (const float*)d_in[5];
    const float* f_dtb  = (const float*)d_in[6];
    const float* f_Al   = (const float*)d_in[7];
    const float* f_Dp   = (const float*)d_in[8];
    const float* f_ow   = (const float*)d_in[9];
    const float* b_in_w = (const float*)d_in[10];
    const float* b_cw   = (const float*)d_in[11];
    const float* b_cb   = (const float*)d_in[12];
    const float* b_xp   = (const float*)d_in[13];
    const float* b_dtw  = (const float*)d_in[14];
    const float* b_dtb  = (const float*)d_in[15];
    const float* b_Al   = (const float*)d_in[16];
    const float* b_Dp   = (const float*)d_in[17];
    const float* b_ow   = (const float*)d_in[18];
    const float* lin_w  = (const float*)d_in[19];
    const float* lin_b  = (const float*)d_in[20];
    float* out = (float*)d_out;

    char* p = (char*)d_ws;
    auto take = [&](size_t bytes) -> char* {
        char* r = p; p += (bytes + 255) & ~(size_t)255; return r;
    };

    // persistent bf16 weights
    unsigned short* wif  = (unsigned short*)take((size_t)2048 * 512 * 2);
    unsigned short* wib  = (unsigned short*)take((size_t)2048 * 512 * 2);
    unsigned short* wxf  = (unsigned short*)take((size_t)64 * 1024 * 2);
    unsigned short* wxb  = (unsigned short*)take((size_t)64 * 1024 * 2);
    unsigned short* wdtf = (unsigned short*)take((size_t)1024 * 32 * 2);
    unsigned short* wdtb = (unsigned short*)take((size_t)1024 * 32 * 2);
    unsigned short* wcmb = (unsigned short*)take((size_t)512 * 2048 * 2);

    const size_t used = (size_t)(p - (char*)d_ws);
    // per-row bytes: xbf 1024 + per dir (xz 4096 + xiy 2048 + dbl 256 + dblh 64)
    const size_t perRow = 1024 + 2 * (4096 + 2048 + 256 + 64);
    int G = 1;
    for (int g = 8; g >= 1; g >>= 1) {
        const size_t need = used + (size_t)g * LSEQ * perRow + 16384;
        if (need <= ws_size || g == 1) { G = g; break; }
    }

    CvtArgs ca;
    ca.s[0] = f_in_w; ca.d[0] = wif;  ca.n[0] = 2048 * 512;
    ca.s[1] = b_in_w; ca.d[1] = wib;  ca.n[1] = 2048 * 512;
    ca.s[2] = f_xp;   ca.d[2] = wxf;  ca.n[2] = 64 * 1024;
    ca.s[3] = b_xp;   ca.d[3] = wxb;  ca.n[3] = 64 * 1024;
    ca.s[4] = f_dtw;  ca.d[4] = wdtf; ca.n[4] = 1024 * 32;
    ca.s[5] = b_dtw;  ca.d[5] = wdtb; ca.n[5] = 1024 * 32;
    cvt_k<<<dim3(128, 6), 256, 0, stream>>>(ca);

    // combined (lin_w @ out_w) weight, bf16, (512 x 2048) — proven r7
    combine_k<<<dim3(4, 128, 2), 256, 0, stream>>>(lin_w, f_ow, b_ow, wcmb);

    char* pg0 = p;
    for (int g0 = 0; g0 < NBATCH; g0 += G) {
        const int Mg = G * LSEQ;
        p = pg0;
        unsigned short* xbf   = (unsigned short*)take((size_t)Mg * 512 * 2);
        unsigned short* xz_f  = (unsigned short*)take((size_t)Mg * 2048 * 2);
        unsigned short* xz_b  = (unsigned short*)take((size_t)Mg * 2048 * 2);
        unsigned short* xiy_f = (unsigned short*)take((size_t)Mg * 1024 * 2);
        unsigned short* xiy_b = (unsigned short*)take((size_t)Mg * 1024 * 2);
        float* dbl_f          = (float*)take((size_t)Mg * 64 * 4);
        float* dbl_b          = (float*)take((size_t)Mg * 64 * 4);
        unsigned short* dblh_f= (unsigned short*)take((size_t)Mg * 32 * 2);
        unsigned short* dblh_b= (unsigned short*)take((size_t)Mg * 32 * 2);

        const float* xg = x + (size_t)g0 * LSEQ * 512;
        float* outg = out + (size_t)g0 * LSEQ * 512;

        cvtx_k<<<dim3(512), 256, 0, stream>>>(xg, xbf, Mg * 512 / 4);

        GemmPair g1 = {};   // in-proj: xz = x @ in_w^T (N=2048), bf16 out
        g1.A[0] = xbf; g1.A[1] = xbf; g1.W[0] = wif; g1.W[1] = wib;
        g1.C[0] = xz_f; g1.C[1] = xz_b;
        gemm_mfma<2,2,1,0,0><<<dim3(Mg/128, 16, 2), 256, 0, stream>>>(g1, 512, 512, 2048, 512);

        conv_silu_k<<<dim3(Mg, 2), 256, 0, stream>>>(xz_f, f_cw, f_cb, xiy_f,
                                                     xz_b, b_cw, b_cb, xiy_b);

        GemmPair g2 = {};   // x-proj: dbl f32 (ldc 64) + bf16 cols<32 (dblh)
        g2.A[0] = xiy_f; g2.A[1] = xiy_b; g2.W[0] = wxf; g2.W[1] = wxb;
        g2.C[0] = dbl_f; g2.C[1] = dbl_b; g2.aux[0] = dblh_f; g2.aux[1] = dblh_b;
        gemm_mfma<4,1,0,0,1><<<dim3(Mg/256, 1, 2), 256, 0, stream>>>(g2, 1024, 1024, 64, 1024);

        ScanPair spp = {};  // scan with in-kernel dt (MFMA per chunk)
        spp.dblh[0] = dblh_f; spp.dblh[1] = dblh_b;
        spp.dtw[0] = wdtf;    spp.dtw[1] = wdtb;
        spp.dtb[0] = f_dtb;   spp.dtb[1] = b_dtb;
        spp.xiy[0] = xiy_f;   spp.xiy[1] = xiy_b;
        spp.dbl[0] = dbl_f;   spp.dbl[1] = dbl_b;
        spp.xz[0] = xz_f;     spp.xz[1] = xz_b;
        spp.Al[0] = f_Al;     spp.Al[1] = b_Al;
        spp.Dp[0] = f_Dp;     spp.Dp[1] = b_Dp;
        scan_k<<<dim3(64, G, 2), 256, 0, stream>>>(spp);

        // fused out-proj+final: out = [y_f | rev(y_b)] @ Wcomb^T + lin_b (K=2048)
        GemmPair g5 = {};
        g5.A[0] = xiy_f; g5.A2[0] = xiy_b; g5.W[0] = wcmb;
        g5.bias[0] = lin_b; g5.C[0] = outg;
        gemm_mfma<2,2,0,1024,0><<<dim3(Mg/128, 4, 1), 256, 0, stream>>>(g5, 1024, 2048, 512, 2048);
    }
}